// Round 1
// baseline (10616.222 us; speedup 1.0000x reference)
//
#include <hip/hip_runtime.h>
#include <hip/hip_bf16.h>

// Sizes (fixed by the problem)
#define B_   64
#define T_   512
#define I_   512
#define H_   512
#define NBLK 128   // 64 blocks per layer; block owns 8 hidden units (32 gate cols)
#define NTHR 256   // 4 waves; wave w owns M-tile rows [16w, 16w+16)

typedef short bf16x8 __attribute__((ext_vector_type(8)));
typedef float f32x4  __attribute__((ext_vector_type(4)));

__device__ __forceinline__ unsigned short f2b(float f) {
    __hip_bfloat16 h = __float2bfloat16(f);   // RNE
    return __builtin_bit_cast(unsigned short, h);
}

__device__ __forceinline__ bf16x8 ld8f(const float* p) {
    float4 a = *(const float4*)p;
    float4 b = *(const float4*)(p + 4);
    bf16x8 r;
    r[0] = (short)f2b(a.x); r[1] = (short)f2b(a.y);
    r[2] = (short)f2b(a.z); r[3] = (short)f2b(a.w);
    r[4] = (short)f2b(b.x); r[5] = (short)f2b(b.y);
    r[6] = (short)f2b(b.z); r[7] = (short)f2b(b.w);
    return r;
}

// Initialize h double-buffers (bf16) and the barrier counter.
__global__ void k_init(const float* __restrict__ h,
                       unsigned short* __restrict__ h0b,
                       unsigned short* __restrict__ h1b,
                       unsigned* __restrict__ cnt) {
    int i = blockIdx.x * 256 + threadIdx.x;   // 65536 threads, h is [2][64][512]
    if (i < 32768) h0b[i] = f2b(h[i]);        // layer0 initial h -> buf 0
    else           h1b[i] = f2b(h[i]);        // layer1 initial h -> buf 1 (offset 32768+(i-32768)=i)
    if (i == 0) *cnt = 0;
}

__global__ __launch_bounds__(NTHR, 1) void k_lstm(
    const float* __restrict__ x,
    const float* __restrict__ Wx0, const float* __restrict__ Wh0, const float* __restrict__ b0,
    const float* __restrict__ Wx1, const float* __restrict__ Wh1, const float* __restrict__ b1,
    const float* __restrict__ c_in,
    unsigned short* __restrict__ h0b, unsigned short* __restrict__ h1b,
    float* __restrict__ cs, unsigned* __restrict__ cnt,
    float* __restrict__ out)
{
    const int tid  = threadIdx.x;
    const int bid  = blockIdx.x;
    const int lay  = bid >> 6;        // 0 or 1
    const int ub   = bid & 63;        // unit block: hidden units [ub*8, ub*8+8)
    const int wave = tid >> 6;        // M-tile index 0..3
    const int lane = tid & 63;
    const int n    = lane & 15;       // A row-in-tile / B col-in-tile
    const int quad = lane >> 4;

    const float* Wx = lay ? Wx1 : Wx0;
    const float* Wh = lay ? Wh1 : Wh0;
    const float* bb = lay ? b1  : b0;
    const float bi = bb[0] + bb[1];
    const float bf = bb[2] + bb[3];
    const float bg = bb[4] + bb[5];
    const float bo = bb[6] + bb[7];

    // ---- Preload this block's weight B-fragments into registers (once). ----
    // breg[ct][f]: frag for col-tile ct (cols ct*16..+16) and K-window f*32..+32
    // (K = [0,512) from Wx, [512,1024) from Wh).
    // B-frag layout: lane holds B[k = quad*8 + j][col = ct*16 + n], j consecutive.
    bf16x8 breg[2][32];
    #pragma unroll
    for (int ct = 0; ct < 2; ++ct) {
        const int c    = ct * 16 + n;                       // 0..31
        const int gcol = (c >> 3) * 512 + ub * 8 + (c & 7); // global gate column
        #pragma unroll
        for (int f = 0; f < 32; ++f) {
            const int kbase = f * 32 + quad * 8;
            bf16x8 w;
            #pragma unroll
            for (int j = 0; j < 8; ++j) {
                const int k = kbase + j;
                const float v = (k < 512) ? Wx[(size_t)k * 2048 + gcol]
                                          : Wh[(size_t)(k - 512) * 2048 + gcol];
                w[j] = (short)f2b(v);
            }
            breg[ct][f] = w;
        }
    }

    const int   mrow0 = wave * 16;
    const int   arow  = mrow0 + n;          // A row this lane supplies
    float* csl = cs + (size_t)lay * 32768;  // this layer's c state [64][512]

    for (int s = 0; s < 513; ++s) {
        const bool active = lay ? (s >= 1) : (s < 512);
        if (active) {
            const int t = lay ? (s - 1) : s;
            const unsigned short* h0r = h0b + (s & 1) * 32768;
            const unsigned short* h1r = h1b + (s & 1) * 32768;

            f32x4 acc0 = {0.f, 0.f, 0.f, 0.f};
            f32x4 acc1 = {0.f, 0.f, 0.f, 0.f};

            if (lay == 0) {
                const float*          px = x   + ((size_t)arow * T_ + t) * I_;
                const unsigned short* ph = h0r + arow * H_;
                #pragma unroll
                for (int f = 0; f < 16; ++f) {
                    bf16x8 a = ld8f(px + f * 32 + quad * 8);
                    acc0 = __builtin_amdgcn_mfma_f32_16x16x32_bf16(a, breg[0][f], acc0, 0, 0, 0);
                    acc1 = __builtin_amdgcn_mfma_f32_16x16x32_bf16(a, breg[1][f], acc1, 0, 0, 0);
                }
                #pragma unroll
                for (int f = 0; f < 16; ++f) {
                    bf16x8 a = *(const bf16x8*)(ph + f * 32 + quad * 8);
                    acc0 = __builtin_amdgcn_mfma_f32_16x16x32_bf16(a, breg[0][16 + f], acc0, 0, 0, 0);
                    acc1 = __builtin_amdgcn_mfma_f32_16x16x32_bf16(a, breg[1][16 + f], acc1, 0, 0, 0);
                }
            } else {
                const unsigned short* p0 = h0r + arow * H_;
                const unsigned short* p1 = h1r + arow * H_;
                #pragma unroll
                for (int f = 0; f < 16; ++f) {
                    bf16x8 a = *(const bf16x8*)(p0 + f * 32 + quad * 8);
                    acc0 = __builtin_amdgcn_mfma_f32_16x16x32_bf16(a, breg[0][f], acc0, 0, 0, 0);
                    acc1 = __builtin_amdgcn_mfma_f32_16x16x32_bf16(a, breg[1][f], acc1, 0, 0, 0);
                }
                #pragma unroll
                for (int f = 0; f < 16; ++f) {
                    bf16x8 a = *(const bf16x8*)(p1 + f * 32 + quad * 8);
                    acc0 = __builtin_amdgcn_mfma_f32_16x16x32_bf16(a, breg[0][16 + f], acc0, 0, 0, 0);
                    acc1 = __builtin_amdgcn_mfma_f32_16x16x32_bf16(a, breg[1][16 + f], acc1, 0, 0, 0);
                }
            }

            // D layout: col = lane&15, row = quad*4 + reg.
            // acc0 cols: n<8 -> gate i (unit n), n>=8 -> gate f (unit n-8)
            // acc1 cols: n<8 -> gate g,            n>=8 -> gate o
            f32x4 x0, x1;
            #pragma unroll
            for (int r = 0; r < 4; ++r) {
                x0[r] = __shfl_xor(acc0[r], 8);   // lane n gets zf (from lane n+8)
                x1[r] = __shfl_xor(acc1[r], 8);   // lane n gets zo
            }
            if (n < 8) {
                const int j  = n;
                const int ug = ub * 8 + j;
                unsigned short* hw = (lay ? h1b : h0b) + ((s + 1) & 1) * 32768;
                #pragma unroll
                for (int r = 0; r < 4; ++r) {
                    const int row = mrow0 + quad * 4 + r;
                    const float zi = acc0[r] + bi;
                    const float zf = x0[r]   + bf;
                    const float zg = acc1[r] + bg;
                    const float zo = x1[r]   + bo;
                    const float ig = 1.f / (1.f + __expf(-zi));
                    const float fg = 1.f / (1.f + __expf(-zf));
                    const float gg = tanhf(zg);
                    const float og = 1.f / (1.f + __expf(-zo));
                    const float cold = (t == 0) ? c_in[(size_t)lay * 32768 + row * 512 + ug]
                                                : csl[row * 512 + ug];
                    const float cn = fg * cold + ig * gg;
                    const float hn = og * tanhf(cn);
                    csl[row * 512 + ug] = cn;
                    hw[row * 512 + ug]  = f2b(hn);
                    if (lay) out[((size_t)row * T_ + t) * H_ + ug] = hn;
                    if (t == 511) {
                        const size_t o1 = (size_t)B_ * T_ * H_;   // 16,777,216
                        out[o1 +         (size_t)lay * 32768 + row * 512 + ug] = hn;
                        out[o1 + 65536 + (size_t)lay * 32768 + row * 512 + ug] = cn;
                    }
                }
            }
        }

        // ---- grid barrier (all 128 blocks), monotonic counter ----
        if (s < 512) {
            __syncthreads();
            if (tid == 0) {
                __builtin_amdgcn_fence(__ATOMIC_RELEASE, "agent");
                __hip_atomic_fetch_add(cnt, 1u, __ATOMIC_RELAXED, __HIP_MEMORY_SCOPE_AGENT);
                const unsigned target = (unsigned)(s + 1) * NBLK;
                while (__hip_atomic_load(cnt, __ATOMIC_RELAXED, __HIP_MEMORY_SCOPE_AGENT) < target) {
                    __builtin_amdgcn_s_sleep(1);
                }
                __builtin_amdgcn_fence(__ATOMIC_ACQUIRE, "agent");
            }
            __syncthreads();
        }
    }
}

extern "C" void kernel_launch(void* const* d_in, const int* in_sizes, int n_in,
                              void* d_out, int out_size, void* d_ws, size_t ws_size,
                              hipStream_t stream) {
    const float* x   = (const float*)d_in[0];
    const float* h   = (const float*)d_in[1];
    const float* c   = (const float*)d_in[2];
    const float* Wx0 = (const float*)d_in[3];
    const float* Wh0 = (const float*)d_in[4];
    const float* b0  = (const float*)d_in[5];
    const float* Wx1 = (const float*)d_in[6];
    const float* Wh1 = (const float*)d_in[7];
    const float* b1  = (const float*)d_in[8];
    float* out = (float*)d_out;

    // Workspace layout (~0.5 MB): h0 double-buf, h1 double-buf (bf16), c state (f32), counter.
    unsigned short* h0b = (unsigned short*)d_ws;          // 2*32768 ushort
    unsigned short* h1b = h0b + 65536;                    // 2*32768 ushort
    float*          cs  = (float*)(h1b + 65536);          // 65536 f32
    unsigned*       cnt = (unsigned*)(cs + 65536);

    k_init<<<256, 256, 0, stream>>>(h, h0b, h1b, cnt);
    k_lstm<<<NBLK, NTHR, 0, stream>>>(x, Wx0, Wh0, b0, Wx1, Wh1, b1, c,
                                      h0b, h1b, cs, cnt, out);
}

// Round 2
// 7700.169 us; speedup vs baseline: 1.3787x; 1.3787x over previous
//
#include <hip/hip_runtime.h>
#include <hip/hip_bf16.h>

// Sizes (fixed by the problem)
#define B_   64
#define T_   512
#define I_   512
#define H_   512
#define NBLK 128   // 64 blocks per layer; block owns 8 hidden units (32 gate cols)
#define NTHR 256   // 4 waves; wave w owns M-tile rows [16w, 16w+16)

typedef short bf16x8 __attribute__((ext_vector_type(8)));
typedef float f32x4  __attribute__((ext_vector_type(4)));
typedef unsigned long long u64;
typedef unsigned short u16;

__device__ __forceinline__ u16 f2b(float f) {
    __hip_bfloat16 h = __float2bfloat16(f);   // RNE
    return __builtin_bit_cast(u16, h);
}

// Agent-scope (device-coherent, LLC-backed) 16B load from two u64 relaxed atomics.
// Bypasses the non-coherent per-XCD L2 -> no fences / cache maintenance needed.
__device__ __forceinline__ bf16x8 coh_ld8(const u16* p) {
    u64 lo = __hip_atomic_load((const u64*)p,     __ATOMIC_RELAXED, __HIP_MEMORY_SCOPE_AGENT);
    u64 hi = __hip_atomic_load((const u64*)p + 1, __ATOMIC_RELAXED, __HIP_MEMORY_SCOPE_AGENT);
    union { u64 q[2]; bf16x8 v; } u;
    u.q[0] = lo; u.q[1] = hi;
    return u.v;
}

// lane i checks the 4 wave-flags of block i (16B) in array f; true if all >= tgt.
__device__ __forceinline__ bool flags_ge(const int* f, int lane, int tgt) {
    const u64* p = (const u64*)(f + 4 * lane);
    u64 a = __hip_atomic_load(p,     __ATOMIC_RELAXED, __HIP_MEMORY_SCOPE_AGENT);
    u64 b = __hip_atomic_load(p + 1, __ATOMIC_RELAXED, __HIP_MEMORY_SCOPE_AGENT);
    int m0 = min((int)(unsigned)a, (int)(a >> 32));
    int m1 = min((int)(unsigned)b, (int)(b >> 32));
    return min(m0, m1) >= tgt;
}

// Init: x fp32 -> bf16, initial h -> ring slot 7 (both layers), flags = 0.
__global__ void k_init(const float* __restrict__ x, const float* __restrict__ h,
                       u16* __restrict__ xb, u16* __restrict__ h0ring, u16* __restrict__ h1ring,
                       int* __restrict__ flags0, int* __restrict__ flags1) {
    long i = (long)blockIdx.x * 256 + threadIdx.x;
    if (i < 2097152) {                          // x: 16,777,216 floats, 8 per thread
        const float* p = x + i * 8;
        float4 a = *(const float4*)p;
        float4 b = *(const float4*)(p + 4);
        union { u16 s[8]; bf16x8 v; } u;
        u.s[0]=f2b(a.x); u.s[1]=f2b(a.y); u.s[2]=f2b(a.z); u.s[3]=f2b(a.w);
        u.s[4]=f2b(b.x); u.s[5]=f2b(b.y); u.s[6]=f2b(b.z); u.s[7]=f2b(b.w);
        *(bf16x8*)(xb + i * 8) = u.v;
    } else if (i < 2097152 + 8192) {            // h: [2][64][512] = 65536 floats
        long j = i - 2097152;
        const float* p = h + j * 8;
        #pragma unroll
        for (int jj = 0; jj < 8; ++jj) {
            long idx = j * 8 + jj;
            u16 v = f2b(p[jj]);
            if (idx < 32768) h0ring[7 * 32768 + idx] = v;
            else             h1ring[7 * 32768 + (idx - 32768)] = v;
        }
    } else if (i < 2097152 + 8192 + 512) {      // flags
        int j = (int)(i - (2097152 + 8192));
        if (j < 256) flags0[j] = 0; else flags1[j - 256] = 0;
    }
}

__global__ __launch_bounds__(NTHR, 1) void k_lstm(
    const u16* __restrict__ xb,
    const float* __restrict__ Wx0, const float* __restrict__ Wh0, const float* __restrict__ b0,
    const float* __restrict__ Wx1, const float* __restrict__ Wh1, const float* __restrict__ b1,
    const float* __restrict__ c_in,
    u16* __restrict__ h0ring, u16* __restrict__ h1ring,
    int* __restrict__ flags0, int* __restrict__ flags1,
    float* __restrict__ cs,
    float* __restrict__ out)
{
    const int tid  = threadIdx.x;
    const int bid  = blockIdx.x;
    const int lay  = bid >> 6;        // 0 or 1
    const int ub   = bid & 63;        // unit block: hidden units [ub*8, ub*8+8)
    const int wave = tid >> 6;        // M-tile index 0..3
    const int lane = tid & 63;
    const int n    = lane & 15;       // A row-in-tile / B col-in-tile
    const int quad = lane >> 4;

    const float* Wx = lay ? Wx1 : Wx0;
    const float* Wh = lay ? Wh1 : Wh0;
    const float* bb = lay ? b1  : b0;
    const float bi = bb[0] + bb[1];
    const float bf = bb[2] + bb[3];
    const float bg = bb[4] + bb[5];
    const float bo = bb[6] + bb[7];

    // ---- Preload this block's weight B-fragments into registers (once). ----
    // breg[ct][f]: frag for col-tile ct (cols ct*16..+16), K-window f*32..+32
    // (K = [0,512) from Wx, [512,1024) from Wh).
    // B-frag layout: lane holds B[k = quad*8 + j][col = ct*16 + n].
    bf16x8 breg[2][32];
    #pragma unroll
    for (int ct = 0; ct < 2; ++ct) {
        const int c    = ct * 16 + n;
        const int gcol = (c >> 3) * 512 + ub * 8 + (c & 7); // global gate column
        #pragma unroll
        for (int f = 0; f < 32; ++f) {
            const int kbase = f * 32 + quad * 8;
            bf16x8 w;
            #pragma unroll
            for (int j = 0; j < 8; ++j) {
                const int k = kbase + j;
                const float v = (k < 512) ? Wx[(size_t)k * 2048 + gcol]
                                          : Wh[(size_t)(k - 512) * 2048 + gcol];
                w[j] = (short)f2b(v);
            }
            breg[ct][f] = w;
        }
    }

    const int mrow0 = wave * 16;
    const int arow  = mrow0 + n;            // A row this lane supplies
    float* csl = cs + (size_t)lay * 32768;  // this layer's c state [64][512] (block-private, L2-cached)
    int* myflag = (lay ? flags1 : flags0) + ub * 4 + wave;

    for (int t = 0; t < 512; ++t) {
        // ---- data-flow wait (no barrier, no fences) ----
        // layer0 @t: flags0 >= t   (h0[t-1] ready), flags1 >= t-6 (ring WAR back-pressure)
        // layer1 @t: flags0 >= t+1 (h0[t] ready),   flags1 >= t   (h1[t-1] ready)
        const int tgt0 = lay ? t + 1 : t;
        const int tgt1 = lay ? t     : t - 6;
        while (!__all(flags_ge(flags0, lane, tgt0) && flags_ge(flags1, lane, tgt1)))
            __builtin_amdgcn_s_sleep(2);
        asm volatile("" ::: "memory");   // keep the loads below the wait

        f32x4 acc0 = {0.f, 0.f, 0.f, 0.f};
        f32x4 acc1 = {0.f, 0.f, 0.f, 0.f};

        if (lay == 0) {
            const u16* px = xb + ((size_t)arow * T_ + t) * I_;            // L2-cached
            const u16* ph = h0ring + ((t - 1) & 7) * 32768 + arow * H_;   // LLC-coherent
            #pragma unroll
            for (int f = 0; f < 16; ++f) {
                bf16x8 a = *(const bf16x8*)(px + f * 32 + quad * 8);
                acc0 = __builtin_amdgcn_mfma_f32_16x16x32_bf16(a, breg[0][f], acc0, 0, 0, 0);
                acc1 = __builtin_amdgcn_mfma_f32_16x16x32_bf16(a, breg[1][f], acc1, 0, 0, 0);
            }
            #pragma unroll
            for (int f = 0; f < 16; ++f) {
                bf16x8 a = coh_ld8(ph + f * 32 + quad * 8);
                acc0 = __builtin_amdgcn_mfma_f32_16x16x32_bf16(a, breg[0][16 + f], acc0, 0, 0, 0);
                acc1 = __builtin_amdgcn_mfma_f32_16x16x32_bf16(a, breg[1][16 + f], acc1, 0, 0, 0);
            }
        } else {
            const u16* p0 = h0ring + (t & 7)       * 32768 + arow * H_;
            const u16* p1 = h1ring + ((t - 1) & 7) * 32768 + arow * H_;
            #pragma unroll
            for (int f = 0; f < 16; ++f) {
                bf16x8 a = coh_ld8(p0 + f * 32 + quad * 8);
                acc0 = __builtin_amdgcn_mfma_f32_16x16x32_bf16(a, breg[0][f], acc0, 0, 0, 0);
                acc1 = __builtin_amdgcn_mfma_f32_16x16x32_bf16(a, breg[1][f], acc1, 0, 0, 0);
            }
            #pragma unroll
            for (int f = 0; f < 16; ++f) {
                bf16x8 a = coh_ld8(p1 + f * 32 + quad * 8);
                acc0 = __builtin_amdgcn_mfma_f32_16x16x32_bf16(a, breg[0][16 + f], acc0, 0, 0, 0);
                acc1 = __builtin_amdgcn_mfma_f32_16x16x32_bf16(a, breg[1][16 + f], acc1, 0, 0, 0);
            }
        }

        // D layout: col = lane&15, row = quad*4 + reg.
        // acc0 cols: n<8 -> gate i (unit n), n>=8 -> gate f (unit n-8)
        // acc1 cols: n<8 -> gate g,          n>=8 -> gate o
        f32x4 x0, x1;
        #pragma unroll
        for (int r = 0; r < 4; ++r) {
            x0[r] = __shfl_xor(acc0[r], 8);   // lane n gets zf
            x1[r] = __shfl_xor(acc1[r], 8);   // lane n gets zo
        }
        if (n < 8) {
            const int ug = ub * 8 + n;
            u16* hw = (lay ? h1ring : h0ring) + (t & 7) * 32768;
            #pragma unroll
            for (int r = 0; r < 4; ++r) {
                const int row = mrow0 + quad * 4 + r;
                const float zi = acc0[r] + bi;
                const float zf = x0[r]   + bf;
                const float zg = acc1[r] + bg;
                const float zo = x1[r]   + bo;
                const float ig = 1.f / (1.f + __expf(-zi));
                const float fg = 1.f / (1.f + __expf(-zf));
                const float gg = tanhf(zg);
                const float og = 1.f / (1.f + __expf(-zo));
                const float cold = (t == 0) ? c_in[(size_t)lay * 32768 + row * 512 + ug]
                                            : csl[row * 512 + ug];
                const float cn = fg * cold + ig * gg;
                const float hn = og * tanhf(cn);
                csl[row * 512 + ug] = cn;                                   // block-private, L2
                __hip_atomic_store(hw + row * 512 + ug, f2b(hn),
                                   __ATOMIC_RELAXED, __HIP_MEMORY_SCOPE_AGENT);
                if (lay) out[((size_t)row * T_ + t) * H_ + ug] = hn;
                if (t == 511) {
                    const size_t o1 = (size_t)B_ * T_ * H_;   // 16,777,216
                    out[o1 +         (size_t)lay * 32768 + row * 512 + ug] = hn;
                    out[o1 + 65536 + (size_t)lay * 32768 + row * 512 + ug] = cn;
                }
            }
        }

        // ---- publish: drain stores to the coherence point, then set our flag ----
        asm volatile("s_waitcnt vmcnt(0)" ::: "memory");
        if (lane == 0)
            __hip_atomic_store(myflag, t + 1, __ATOMIC_RELAXED, __HIP_MEMORY_SCOPE_AGENT);
    }
}

extern "C" void kernel_launch(void* const* d_in, const int* in_sizes, int n_in,
                              void* d_out, int out_size, void* d_ws, size_t ws_size,
                              hipStream_t stream) {
    const float* x   = (const float*)d_in[0];
    const float* h   = (const float*)d_in[1];
    const float* c   = (const float*)d_in[2];
    const float* Wx0 = (const float*)d_in[3];
    const float* Wh0 = (const float*)d_in[4];
    const float* b0  = (const float*)d_in[5];
    const float* Wx1 = (const float*)d_in[6];
    const float* Wh1 = (const float*)d_in[7];
    const float* b1  = (const float*)d_in[8];
    float* out = (float*)d_out;

    // ws layout (~35 MB): xb bf16, h rings (depth 8, bf16), flags, c state (f32).
    u16* xb     = (u16*)d_ws;                 // 16,777,216 u16
    u16* h0ring = xb + 16777216;              // 8*32768 u16
    u16* h1ring = h0ring + 262144;            // 8*32768 u16
    int* flags0 = (int*)(h1ring + 262144);    // 256 ints (64 blocks x 4 waves)
    int* flags1 = flags0 + 256;               // 256 ints
    float* cs   = (float*)(flags1 + 256);     // 65536 f32

    k_init<<<8226, 256, 0, stream>>>(x, h, xb, h0ring, h1ring, flags0, flags1);
    k_lstm<<<NBLK, NTHR, 0, stream>>>(xb, Wx0, Wh0, b0, Wx1, Wh1, b1, c,
                                      h0ring, h1ring, flags0, flags1, cs, out);
}